// Round 9
// baseline (63.191 us; speedup 1.0000x reference)
//
#include <hip/hip_runtime.h>

// PatchLoss: B=64, H=W=512, p=8 -> per batch 4096 patches of 64 elems.
// argmax_p sum|o-t| vs argmax_p sum(t) (mean = sum/64, argmax-invariant).
// Outputs {64, num_true, 64-num_true, num_true/64} as float32.
//
// R9 = R6 (best, 27.0us) + fused last-block finalize (kills the 2nd
// dispatch + graph-node gap). R6 core: 512 blocks x 256 thr = 2048 waves;
// wave g owns the 4 half-bands {s+32k} of batch g>>5 (half-band = 8 rows
// x 256 cols, one float4/lane/row); register ping-pong A/B, ~6-deep load
// window (the compiler's pressure heuristic caps VGPR; empirically at the
// ~5.8 TB/s memory ceiling anyway — R7's 32KB-in-flight DMA variant and
// R8's 4096-wave variant both plateau at/below this).

typedef unsigned long long u64;

__device__ __forceinline__ unsigned ordf(float f) {
    unsigned u = __float_as_uint(f);
    return u ^ ((u >> 31) ? 0xFFFFFFFFu : 0x80000000u);
}

__device__ __forceinline__ u64 umax64(u64 a, u64 b) { return a > b ? a : b; }

__device__ __forceinline__ void loadc(float4 (&O)[8], float4 (&G)[8],
                                      const float* po, const float* pt) {
#pragma unroll
    for (int r = 0; r < 8; ++r)
        O[r] = *reinterpret_cast<const float4*>(po + (size_t)r * 512);
#pragma unroll
    for (int r = 0; r < 8; ++r)
        G[r] = *reinterpret_cast<const float4*>(pt + (size_t)r * 512);
}

__device__ __forceinline__ void consume(const float4 (&O)[8], const float4 (&G)[8],
                                        int ws_, int l, int k,
                                        u64& kl, u64& km) {
    float sA = 0.f, sT = 0.f;
#pragma unroll
    for (int r = 0; r < 8; ++r) {
        sA += fabsf(O[r].x - G[r].x) + fabsf(O[r].y - G[r].y)
            + fabsf(O[r].z - G[r].z) + fabsf(O[r].w - G[r].w);
        sT += G[r].x + G[r].y + G[r].z + G[r].w;
    }
    // lanes l and l^1 hold the two float4 columns of one patch: combine.
    sA += __shfl_xor(sA, 1);
    sT += __shfl_xor(sT, 1);
    const int tb  = ws_ + 32 * k;                                // half-band
    const int idx = (tb >> 1) * 64 + (tb & 1) * 32 + (l >> 1);   // patch idx
    kl = umax64(kl, ((u64)ordf(sA) << 32) | (unsigned)(4095 - idx));
    km = umax64(km, ((u64)ordf(sT) << 32) | (unsigned)(4095 - idx));
}

__global__ __launch_bounds__(256, 2)
void patch_kernel(const float* __restrict__ outp,
                  const float* __restrict__ tgt,
                  u64* __restrict__ wsL, u64* __restrict__ wsM,
                  unsigned* __restrict__ counter,
                  float* __restrict__ out) {
    const int t   = threadIdx.x;
    const int g   = blockIdx.x * 4 + (t >> 6);   // wave id 0..2047
    const int l   = t & 63;
    const int b   = g >> 5;                      // batch (32 waves/batch)
    const int ws_ = g & 31;                      // wave slot in batch

    // half-band tb = ws_+32k: base = b*512*512 + (tb>>1)*8*512 + (tb&1)*256
    // tile step k->k+1: +16 patch rows = +65536 floats.
    const size_t base0 = (size_t)b * 262144 + (size_t)(ws_ >> 1) * 4096
                       + (size_t)(ws_ & 1) * 256 + (size_t)l * 4;
    const float* po = outp + base0;
    const float* pt = tgt  + base0;

    float4 oA[8], gA[8], oB[8], gB[8];
    u64 kl = 0, km = 0;

    loadc(oA, gA, po,          pt);              // tile0 -> A
    loadc(oB, gB, po + 65536,  pt + 65536);      // tile1 -> B (in flight)
    consume(oA, gA, ws_, l, 0, kl, km);          // consume tile0
    loadc(oA, gA, po + 131072, pt + 131072);     // tile2 -> A
    consume(oB, gB, ws_, l, 1, kl, km);          // consume tile1
    loadc(oB, gB, po + 196608, pt + 196608);     // tile3 -> B
    consume(oA, gA, ws_, l, 2, kl, km);          // consume tile2
    consume(oB, gB, ws_, l, 3, kl, km);          // consume tile3

    // per-wave butterfly argmax (all candidates same-batch); s=1 skipped
    // (lane pairs hold identical candidates after the shfl combine).
#pragma unroll
    for (int s = 32; s > 1; s >>= 1) {
        kl = umax64(kl, __shfl_xor(kl, s));
        km = umax64(km, __shfl_xor(km, s));
    }
    if (l == 0) { wsL[g] = kl; wsM[g] = km; }

    // ---- last-block-done fused finalize (rocPRIM pattern) ----
    __syncthreads();                // all 4 waves' result stores issued
    __threadfence();                // release: make stores device-visible
    __shared__ int is_last;
    if (t == 0) {
        const unsigned old = atomicAdd(counter, 1u);   // device scope
        is_last = (old == 511u);
    }
    __syncthreads();
    if (!is_last) return;
    __threadfence();                // acquire before reading others' results

    const int q    = t >> 2;        // batch
    const int part = t & 3;
    u64 ml = 0, mm = 0;
    const int base = q * 32 + part * 8;
#pragma unroll
    for (int i = 0; i < 8; ++i) {
        ml = umax64(ml, wsL[base + i]);
        mm = umax64(mm, wsM[base + i]);
    }
    ml = umax64(ml, __shfl_xor(ml, 1));
    ml = umax64(ml, __shfl_xor(ml, 2));
    mm = umax64(mm, __shfl_xor(mm, 1));
    mm = umax64(mm, __shfl_xor(mm, 2));

    __shared__ int flags[64];
    if (part == 0)
        flags[q] = ((unsigned)ml == (unsigned)mm) ? 1 : 0;  // low32 = 4095-idx
    __syncthreads();

    if (t < 64) {
        int v = flags[t];
#pragma unroll
        for (int s = 32; s > 0; s >>= 1) v += __shfl_down(v, s);
        if (t == 0) {
            const float nt = (float)v;
            out[0] = 64.0f;
            out[1] = nt;
            out[2] = 64.0f - nt;
            out[3] = nt / 64.0f;
        }
    }
}

extern "C" void kernel_launch(void* const* d_in, const int* in_sizes, int n_in,
                              void* d_out, int out_size, void* d_ws, size_t ws_size,
                              hipStream_t stream) {
    const float* outp = (const float*)d_in[0];
    const float* tgt  = (const float*)d_in[1];
    // d_in[2] = patch_size (==8), hardcoded.

    u64* wsL = (u64*)d_ws;                       // 2048 u64
    u64* wsM = wsL + 2048;                       // 2048 u64
    unsigned* counter = (unsigned*)(wsM + 2048); // 1 u32

    // counter must be 0 at kernel start on EVERY call (harness poisons d_ws
    // to 0xAA once; graph replays don't re-poison). 4-byte async memset.
    hipMemsetAsync(counter, 0, sizeof(unsigned), stream);

    patch_kernel<<<512, 256, 0, stream>>>(outp, tgt, wsL, wsM, counter,
                                          (float*)d_out);
}

// Round 10
// 27.046 us; speedup vs baseline: 2.3365x; 2.3365x over previous
//
#include <hip/hip_runtime.h>

// PatchLoss: B=64, H=W=512, p=8 -> per batch 4096 patches of 64 elems.
// argmax_p sum|o-t| vs argmax_p sum(t) (mean = sum/64 is argmax-invariant).
// Outputs {64, num_true, 64-num_true, num_true/64} as float32.
//
// FINAL = R6 structure (measured optimum, 27.0us):
//   512 blocks x 256 thr = 2048 waves; wave g owns the 4 half-bands
//   {s+32k} of batch g>>5 (half-band = 8 rows x 256 cols, one
//   float4/lane/row); register ping-pong A/B software pipeline.
// Evidence trail: R7 (LDS-DMA, 32KB/wave in flight) 27.9; R8 (sequential
// bands, 4096 waves) 33.1; R9 (fused last-block finalize w/ threadfence)
// 63.2 — device-scope release per block = per-block L2 flush on
// non-coherent XCDs, catastrophic. Patch kernel streams 134MB at
// ~5.7 TB/s effective (~90% of the 6.29 TB/s copy ceiling); residual
// ~3-4us is the finalize dispatch + graph-node gap (proven unfusable).

typedef unsigned long long u64;

__device__ __forceinline__ unsigned ordf(float f) {
    unsigned u = __float_as_uint(f);
    return u ^ ((u >> 31) ? 0xFFFFFFFFu : 0x80000000u);
}

__device__ __forceinline__ u64 umax64(u64 a, u64 b) { return a > b ? a : b; }

__device__ __forceinline__ void loadc(float4 (&O)[8], float4 (&G)[8],
                                      const float* po, const float* pt) {
#pragma unroll
    for (int r = 0; r < 8; ++r)
        O[r] = *reinterpret_cast<const float4*>(po + (size_t)r * 512);
#pragma unroll
    for (int r = 0; r < 8; ++r)
        G[r] = *reinterpret_cast<const float4*>(pt + (size_t)r * 512);
}

__device__ __forceinline__ void consume(const float4 (&O)[8], const float4 (&G)[8],
                                        int ws_, int l, int k,
                                        u64& kl, u64& km) {
    float sA = 0.f, sT = 0.f;
#pragma unroll
    for (int r = 0; r < 8; ++r) {
        sA += fabsf(O[r].x - G[r].x) + fabsf(O[r].y - G[r].y)
            + fabsf(O[r].z - G[r].z) + fabsf(O[r].w - G[r].w);
        sT += G[r].x + G[r].y + G[r].z + G[r].w;
    }
    // lanes l and l^1 hold the two float4 columns of one patch: combine.
    sA += __shfl_xor(sA, 1);
    sT += __shfl_xor(sT, 1);
    const int tb  = ws_ + 32 * k;                                // half-band
    const int idx = (tb >> 1) * 64 + (tb & 1) * 32 + (l >> 1);   // patch idx
    kl = umax64(kl, ((u64)ordf(sA) << 32) | (unsigned)(4095 - idx));
    km = umax64(km, ((u64)ordf(sT) << 32) | (unsigned)(4095 - idx));
}

__global__ __launch_bounds__(256, 2)
void patch_kernel(const float* __restrict__ outp,
                  const float* __restrict__ tgt,
                  u64* __restrict__ wsL, u64* __restrict__ wsM) {
    const int t   = threadIdx.x;
    const int g   = blockIdx.x * 4 + (t >> 6);   // wave id 0..2047
    const int l   = t & 63;
    const int b   = g >> 5;                      // batch (32 waves/batch)
    const int ws_ = g & 31;                      // wave slot in batch

    // half-band tb = ws_+32k: base = b*512*512 + (tb>>1)*8*512 + (tb&1)*256
    // tile step k->k+1: +16 patch rows = +65536 floats.
    const size_t base0 = (size_t)b * 262144 + (size_t)(ws_ >> 1) * 4096
                       + (size_t)(ws_ & 1) * 256 + (size_t)l * 4;
    const float* po = outp + base0;
    const float* pt = tgt  + base0;

    float4 oA[8], gA[8], oB[8], gB[8];
    u64 kl = 0, km = 0;

    loadc(oA, gA, po,          pt);              // tile0 -> A
    loadc(oB, gB, po + 65536,  pt + 65536);      // tile1 -> B (in flight)
    consume(oA, gA, ws_, l, 0, kl, km);          // consume tile0
    loadc(oA, gA, po + 131072, pt + 131072);     // tile2 -> A
    consume(oB, gB, ws_, l, 1, kl, km);          // consume tile1
    loadc(oB, gB, po + 196608, pt + 196608);     // tile3 -> B
    consume(oA, gA, ws_, l, 2, kl, km);          // consume tile2
    consume(oB, gB, ws_, l, 3, kl, km);          // consume tile3

    // per-wave butterfly argmax (all candidates same-batch); s=1 skipped
    // (lane pairs hold identical candidates after the shfl combine).
#pragma unroll
    for (int s = 32; s > 1; s >>= 1) {
        kl = umax64(kl, __shfl_xor(kl, s));
        km = umax64(km, __shfl_xor(km, s));
    }
    if (l == 0) { wsL[g] = kl; wsM[g] = km; }
}

__global__ void finalize_kernel(const u64* __restrict__ wsL,
                                const u64* __restrict__ wsM,
                                float* __restrict__ outp) {
    const int t    = threadIdx.x;  // 0..255
    const int q    = t >> 2;       // batch
    const int part = t & 3;

    u64 ml = 0, mm = 0;
    const int base = q * 32 + part * 8;
#pragma unroll
    for (int i = 0; i < 8; ++i) {
        ml = umax64(ml, wsL[base + i]);
        mm = umax64(mm, wsM[base + i]);
    }
    ml = umax64(ml, __shfl_xor(ml, 1));
    ml = umax64(ml, __shfl_xor(ml, 2));
    mm = umax64(mm, __shfl_xor(mm, 1));
    mm = umax64(mm, __shfl_xor(mm, 2));

    __shared__ int flags[64];
    if (part == 0)
        flags[q] = ((unsigned)ml == (unsigned)mm) ? 1 : 0;  // low32 = 4095-idx
    __syncthreads();

    if (t < 64) {
        int v = flags[t];
#pragma unroll
        for (int s = 32; s > 0; s >>= 1) v += __shfl_down(v, s);
        if (t == 0) {
            const float nt = (float)v;
            outp[0] = 64.0f;
            outp[1] = nt;
            outp[2] = 64.0f - nt;
            outp[3] = nt / 64.0f;
        }
    }
}

extern "C" void kernel_launch(void* const* d_in, const int* in_sizes, int n_in,
                              void* d_out, int out_size, void* d_ws, size_t ws_size,
                              hipStream_t stream) {
    const float* outp = (const float*)d_in[0];
    const float* tgt  = (const float*)d_in[1];
    // d_in[2] = patch_size (==8), hardcoded.

    u64* wsL = (u64*)d_ws;        // 2048 u64
    u64* wsM = wsL + 2048;        // 2048 u64

    patch_kernel<<<512, 256, 0, stream>>>(outp, tgt, wsL, wsM);
    finalize_kernel<<<1, 256, 0, stream>>>(wsL, wsM, (float*)d_out);
}